// Round 1
// 215.334 us; speedup vs baseline: 1.0665x; 1.0665x over previous
//
#include <hip/hip_runtime.h>
#include <hip/hip_fp16.h>
#include <math.h>

#define THREADS 256
#define CHUNK_SHIFT 14
#define CHUNK (1 << CHUNK_SHIFT)
#define LDS_WORDS 12500   // ceil(N/4) for N=50000, 8-bit packed counters
#define MAXB 16           // max chunks per quarter in k_pre (holds for P <= 64)
#define XS_STRIDE 68

// ---- privatized LDS histogram, 4 bins/word (8-bit); dst blocks capture rank ----
// Also zeroes the global row-base counter used by k_pre's atomic block-base claim.
__global__ __launch_bounds__(1024)
void k_hist(const int* __restrict__ src, const int* __restrict__ dst,
            unsigned int* __restrict__ partS, unsigned int* __restrict__ partD,
            unsigned char* __restrict__ rank, unsigned int* __restrict__ counter,
            int E, int P, int words) {
    __shared__ unsigned int hist[LDS_WORDS];
    if (blockIdx.x == 0 && threadIdx.x == 0) *counter = 0u;
    int isSrc = (blockIdx.x >= (unsigned)P);
    int b = isSrc ? (blockIdx.x - P) : blockIdx.x;
    int tid = threadIdx.x;

    for (int w = tid; w < words; w += 1024) hist[w] = 0u;
    __syncthreads();

    int start = b << CHUNK_SHIFT;
    int end = start + CHUNK; if (end > E) end = E;

    if (isSrc) {
        for (int e = start + tid; e < end; e += 1024) {
            int s = src[e];
            atomicAdd(&hist[s >> 2], 1u << ((s & 3) * 8));
        }
    } else {
        for (int e = start + tid; e < end; e += 1024) {
            int d = dst[e];
            unsigned int old = atomicAdd(&hist[d >> 2], 1u << ((d & 3) * 8));
            rank[e] = (unsigned char)((old >> ((d & 3) * 8)) & 0xFFu);
        }
    }
    __syncthreads();

    unsigned int* part = isSrc ? partS : partD;
    for (int w = tid; w < words; w += 1024)
        part[(size_t)b * words + w] = hist[w];
}

// ---- k_pre v2: one packed word (4 nodes) per thread, chunk range split 4-way.
// Chain depth 98 -> 13, fully coalesced 256B wave loads, SWAR byte prefix in regs.
// Block = 64 words x 4 quarters = 256 nodes; block row-base claimed by atomicAdd
// (CSR row order is irrelevant for sum-aggregation), eliminating k_scan2.
__global__ __launch_bounds__(THREADS)
void k_pre(const unsigned int* __restrict__ partS,
           const unsigned int* __restrict__ partD,
           unsigned int* __restrict__ prefD,
           int* __restrict__ deg_d, float* __restrict__ ns, float* __restrict__ nd,
           int* __restrict__ rp, int* __restrict__ bsum,
           unsigned int* __restrict__ counter,
           int P, int words, int N) {
    __shared__ unsigned int qsD[4][64];
    __shared__ unsigned int qsS[4][64];
    int t = threadIdx.x;
    int widx = t & 63;          // word within this block's 64-word span
    int q = t >> 6;             // chunk-range quarter
    int w = blockIdx.x * 64 + widx;
    bool valid = (w < words);

    int per = (P + 3) >> 2;     // <= MAXB for P <= 64
    int blo = q * per;
    int cnt = P - blo; if (cnt > per) cnt = per; if (cnt < 0) cnt = 0;

    unsigned int vD[MAXB];      // compile-time-indexed -> registers
    unsigned int runD = 0, runS = 0;
#pragma unroll
    for (int bb = 0; bb < MAXB; bb++) {
        unsigned int vd = 0, vs = 0;
        if (bb < cnt && valid) {
            size_t off = (size_t)(blo + bb) * words + w;
            vd = partD[off];
            vs = partS[off];
        }
        vD[bb] = vd;
        runD += vd;             // SWAR byte add: per-node totals < 256, no carry
        runS += vs;
    }
    qsD[q][widx] = runD;
    qsS[q][widx] = runS;
    __syncthreads();

    unsigned int baseD = 0, totD = 0, totS = 0;
#pragma unroll
    for (int qq = 0; qq < 4; qq++) {
        unsigned int xd = qsD[qq][widx];
        unsigned int xs = qsS[qq][widx];
        if (qq < q) baseD += xd;
        totD += xd;
        totS += xs;
    }

    // packed exclusive-prefix words for this quarter's chunk range
    unsigned int pref = baseD;
#pragma unroll
    for (int bb = 0; bb < MAXB; bb++) {
        if (bb < cnt && valid)
            prefD[(size_t)(blo + bb) * words + w] = pref;
        pref += vD[bb];
    }

    if (q == 0) {   // threads 0..63 == wave 0: per-node outputs + block scan
        int b0 = (int)(totD & 0xFFu), b1 = (int)((totD >> 8) & 0xFFu),
            b2 = (int)((totD >> 16) & 0xFFu), b3 = (int)((totD >> 24) & 0xFFu);
        int wsum = b0 + b1 + b2 + b3;
        int incl = wsum;
#pragma unroll
        for (int off = 1; off < 64; off <<= 1) {
            int y = __shfl_up(incl, off);
            if (widx >= off) incl += y;
        }
        int excl = incl - wsum;
        int btot = __shfl(incl, 63);
        if (widx == 0)
            bsum[blockIdx.x] = (int)atomicAdd(counter, (unsigned int)btot);
        if (valid) {
            int s0 = (int)(totS & 0xFFu), s1 = (int)((totS >> 8) & 0xFFu),
                s2 = (int)((totS >> 16) & 0xFFu), s3 = (int)((totS >> 24) & 0xFFu);
            int4 dv; dv.x = b0; dv.y = b1; dv.z = b2; dv.w = b3;
            *(int4*)&deg_d[(size_t)4 * w] = dv;
            float4 ndv;
            ndv.x = b0 ? 1.0f / sqrtf((float)b0) : 0.0f;
            ndv.y = b1 ? 1.0f / sqrtf((float)b1) : 0.0f;
            ndv.z = b2 ? 1.0f / sqrtf((float)b2) : 0.0f;
            ndv.w = b3 ? 1.0f / sqrtf((float)b3) : 0.0f;
            *(float4*)&nd[(size_t)4 * w] = ndv;
            float4 nsv;
            nsv.x = s0 ? 1.0f / sqrtf((float)s0) : 0.0f;
            nsv.y = s1 ? 1.0f / sqrtf((float)s1) : 0.0f;
            nsv.z = s2 ? 1.0f / sqrtf((float)s2) : 0.0f;
            nsv.w = s3 ? 1.0f / sqrtf((float)s3) : 0.0f;
            *(float4*)&ns[(size_t)4 * w] = nsv;
            int4 rv; rv.x = excl; rv.y = excl + b0;
            rv.z = excl + b0 + b1; rv.w = excl + b0 + b1 + b2;
            *(int4*)&rp[(size_t)4 * w] = rv;
        }
    }
}

// ---- merged: CSR fill (blocks [0,gFill)) || layer-1 GEMM (blocks [gFill, ...)) ----
// Independent work, same deps (k_pre); latency-bound fill overlaps LDS-bound GEMM.
__global__ __launch_bounds__(256, 4)
void k_fill_gemm(const int* __restrict__ src, const int* __restrict__ dst,
                 const int* __restrict__ rp, const int* __restrict__ bsum,
                 const unsigned char* __restrict__ rank,
                 const unsigned int* __restrict__ prefD,
                 int* __restrict__ col, int E, int words, int gFill,
                 const float* __restrict__ X, const float* __restrict__ norm,
                 const float* __restrict__ W, __half* __restrict__ H, int N) {
    __shared__ float Xs[64 * XS_STRIDE];
    __shared__ float Ws[64 * 64];
    int tid = threadIdx.x;

    if ((int)blockIdx.x < gFill) {
        int e = blockIdx.x * 256 + tid;
        if (e < E) {
            int d = dst[e];
            int b = e >> CHUNK_SHIFT;
            unsigned int pk = prefD[(size_t)b * words + (d >> 2)];
            int pref = (int)((pk >> ((d & 3) * 8)) & 0xFFu);
            col[rp[d] + bsum[d >> 8] + pref + (int)rank[e]] = src[e];
        }
        return;
    }

    int rowBase = ((int)blockIdx.x - gFill) * 64;
    for (int i = tid; i < 1024; i += 256)
        ((float4*)Ws)[i] = ((const float4*)W)[i];
    for (int i = tid; i < 1024; i += 256) {
        int r  = i >> 4;
        int k4 = i & 15;
        int row = rowBase + r;
        float4 v = make_float4(0.f, 0.f, 0.f, 0.f);
        if (row < N) {
            v = ((const float4*)X)[(size_t)row * 16 + k4];
            float nv = norm[row];
            v.x *= nv; v.y *= nv; v.z *= nv; v.w *= nv;
        }
        *((float4*)&Xs[r * XS_STRIDE + (k4 << 2)]) = v;
    }
    __syncthreads();

    int tc = tid & 15;
    int tr = tid >> 4;
    int c0 = tc * 4, r0 = tr * 4;
    float acc[4][4] = {};

#pragma unroll 2
    for (int k = 0; k < 64; k += 4) {
        float4 wv[4];
#pragma unroll
        for (int kk = 0; kk < 4; kk++)
            wv[kk] = *((const float4*)&Ws[(k + kk) * 64 + c0]);
#pragma unroll
        for (int j = 0; j < 4; j++) {
            float4 xv = *((const float4*)&Xs[(r0 + j) * XS_STRIDE + k]);
            acc[j][0] += xv.x * wv[0].x; acc[j][1] += xv.x * wv[0].y;
            acc[j][2] += xv.x * wv[0].z; acc[j][3] += xv.x * wv[0].w;
            acc[j][0] += xv.y * wv[1].x; acc[j][1] += xv.y * wv[1].y;
            acc[j][2] += xv.y * wv[1].z; acc[j][3] += xv.y * wv[1].w;
            acc[j][0] += xv.z * wv[2].x; acc[j][1] += xv.z * wv[2].y;
            acc[j][2] += xv.z * wv[2].z; acc[j][3] += xv.z * wv[2].w;
            acc[j][0] += xv.w * wv[3].x; acc[j][1] += xv.w * wv[3].y;
            acc[j][2] += xv.w * wv[3].z; acc[j][3] += xv.w * wv[3].w;
        }
    }
#pragma unroll
    for (int j = 0; j < 4; j++) {
        int row = rowBase + r0 + j;
        if (row < N) {
            __half2 h01 = __floats2half2_rn(acc[j][0], acc[j][1]);
            __half2 h23 = __floats2half2_rn(acc[j][2], acc[j][3]);
            uint2 pk;
            pk.x = *(unsigned int*)&h01;
            pk.y = *(unsigned int*)&h23;
            *((uint2*)(H + (size_t)row * 64 + c0)) = pk;
        }
    }
}

// ---- fused agg + next-layer GEMM (FC=0) or agg + final FC (FC=1).
// Block owns 64 consecutive nodes: each wave gathers/reduces 16 nodes into the
// LDS Xs tile (scaled by ns for FC=0), then the 64x64 tile GEMM / 64x10 FC runs
// in-block with W amortized in LDS. Removes the bufX global round-trip.
template<int FC>
__global__ __launch_bounds__(256, 4)
void k_agg_gemm(const uint4* __restrict__ H4, const int* __restrict__ rp,
                const int* __restrict__ bsum, const int* __restrict__ deg,
                const int* __restrict__ col, const float* __restrict__ nd,
                const float* __restrict__ nsrc, const float* __restrict__ bias,
                const float* __restrict__ W, const float* __restrict__ Wb2,
                void* __restrict__ OutP, int N) {
    __shared__ float Xs[64 * XS_STRIDE];
    __shared__ float Ws[FC ? 640 : 4096];
    __shared__ float Wb[16];
    int tid = threadIdx.x;

    if constexpr (FC == 0) {
        for (int i = tid; i < 1024; i += 256)
            ((float4*)Ws)[i] = ((const float4*)W)[i];
    } else {
        // store transposed: Ws[c*64 + k] = Wfc[k][c]  (enables float4 k-reads)
        for (int i = tid; i < 640; i += 256) {
            int k = i / 10, c = i - k * 10;
            Ws[c * 64 + k] = W[i];
        }
        if (tid < 10) Wb[tid] = Wb2[tid];
    }

    int wave = tid >> 6;
    int lane = tid & 63;
    int g = lane >> 3;   // edge subgroup 0..7
    int l = lane & 7;    // uint4 index within 128B row
    int g0 = (lane >> 3) & 1, g1 = (lane >> 4) & 1, g2 = (lane >> 5) & 1;
    int ch = (l << 3) + (g0 << 2) + (g1 << 1) + g2;
    float bv = bias[ch];
    int rowBase = blockIdx.x * 64;

    // ---- phase A: each wave aggregates 16 nodes into Xs rows
    int node = rowBase + wave * 16;
    int start = 0, n = 0;
    float nv = 0.f, nsv = 0.f;
    if (node < N) {
        start = rp[node] + bsum[node >> 8];
        n = deg[node];
        nv = nd[node];
        if constexpr (FC == 0) nsv = nsrc[node];
    }

#pragma unroll 1
    for (int i = 0; i < 16; i++) {
        // prefetch next node's meta (independent; overlaps current gathers)
        int nextNode = node + 1;
        int nStart = 0, nN = 0;
        float nNv = 0.f, nNs = 0.f;
        if (i < 15 && nextNode < N) {
            nStart = rp[nextNode] + bsum[nextNode >> 8];
            nN = deg[nextNode];
            nNv = nd[nextNode];
            if constexpr (FC == 0) nNs = nsrc[nextNode];
        }

        int sStart = __builtin_amdgcn_readfirstlane(start);
        int sN     = __builtin_amdgcn_readfirstlane(n);
        float a[8] = {0.f, 0.f, 0.f, 0.f, 0.f, 0.f, 0.f, 0.f};

        auto accum = [&](uint4 v) {
            float2 f0 = __half22float2(*(__half2*)&v.x);
            float2 f1 = __half22float2(*(__half2*)&v.y);
            float2 f2 = __half22float2(*(__half2*)&v.z);
            float2 f3 = __half22float2(*(__half2*)&v.w);
            a[0] += f0.x; a[1] += f0.y; a[2] += f1.x; a[3] += f1.y;
            a[4] += f2.x; a[5] += f2.y; a[6] += f3.x; a[7] += f3.y;
        };

        if (sN <= 32) {
            int idx = (lane < sN) ? col[sStart + lane] : 0;
            int s0 = __shfl(idx, g);
            uint4 z; z.x = 0u; z.y = 0u; z.z = 0u; z.w = 0u;
            uint4 v0 = z, v1 = z, v2 = z, v3 = z;
            if (g < sN) v0 = H4[(size_t)s0 * 8 + l];
            if (sN > 8) {
                int s1 = __shfl(idx, 8 + g);
                if (8 + g < sN) v1 = H4[(size_t)s1 * 8 + l];
            }
            if (sN > 16) {
                int s2 = __shfl(idx, 16 + g);
                if (16 + g < sN) v2 = H4[(size_t)s2 * 8 + l];
            }
            if (sN > 24) {
                int s3 = __shfl(idx, 24 + g);
                if (24 + g < sN) v3 = H4[(size_t)s3 * 8 + l];
            }
            accum(v0);
            if (sN > 8)  accum(v1);
            if (sN > 16) accum(v2);
            if (sN > 24) accum(v3);
        } else {
            for (int base = 0; base < sN; base += 64) {
                int cnt = sN - base;
                if (cnt > 64) cnt = 64;
                int idx = (lane < cnt) ? col[sStart + base + lane] : 0;
                int j = 0;
                for (; j + 32 <= cnt; j += 32) {
                    int s0 = __shfl(idx, j + g);
                    int s1 = __shfl(idx, j + 8 + g);
                    int s2 = __shfl(idx, j + 16 + g);
                    int s3 = __shfl(idx, j + 24 + g);
                    uint4 v0 = H4[(size_t)s0 * 8 + l];
                    uint4 v1 = H4[(size_t)s1 * 8 + l];
                    uint4 v2 = H4[(size_t)s2 * 8 + l];
                    uint4 v3 = H4[(size_t)s3 * 8 + l];
                    accum(v0); accum(v1); accum(v2); accum(v3);
                }
                for (; j + 8 <= cnt; j += 8) {
                    int s0 = __shfl(idx, j + g);
                    uint4 v0 = H4[(size_t)s0 * 8 + l];
                    accum(v0);
                }
                int tl = cnt - j;
                if (tl > 0) {
                    int s0 = __shfl(idx, j + (g < tl ? g : 0));
                    if (g < tl) {
                        uint4 v0 = H4[(size_t)s0 * 8 + l];
                        accum(v0);
                    }
                }
            }
        }

        // transpose-reduce: 3 butterfly steps -> one channel per lane
        float b_[4];
#pragma unroll
        for (int j = 0; j < 4; j++) {
            float send = g0 ? a[j] : a[j + 4];
            float recv = __shfl_xor(send, 8);
            float keep = g0 ? a[j + 4] : a[j];
            b_[j] = keep + recv;
        }
        float c_[2];
#pragma unroll
        for (int j = 0; j < 2; j++) {
            float send = g1 ? b_[j] : b_[j + 2];
            float recv = __shfl_xor(send, 16);
            float keep = g1 ? b_[j + 2] : b_[j];
            c_[j] = keep + recv;
        }
        float send = g2 ? c_[0] : c_[1];
        float recv = __shfl_xor(send, 32);
        float keep = g2 ? c_[1] : c_[0];
        float s = keep + recv;

        float tv = tanhf(s * nv + bv);
        float val;
        if constexpr (FC == 0) val = tv * nsv;   // pre-scale by ns for next GEMM
        else                   val = tv;
        Xs[(wave * 16 + i) * XS_STRIDE + ch] = (node < N) ? val : 0.0f;

        node = nextNode; start = nStart; n = nN; nv = nNv; nsv = nNs;
    }
    __syncthreads();

    // ---- phase B
    if constexpr (FC == 0) {
        __half* Hh = (__half*)OutP;
        int tc = tid & 15;
        int tr = tid >> 4;
        int c0 = tc * 4, r0 = tr * 4;
        float acc[4][4] = {};

#pragma unroll 2
        for (int k = 0; k < 64; k += 4) {
            float4 wv[4];
#pragma unroll
            for (int kk = 0; kk < 4; kk++)
                wv[kk] = *((const float4*)&Ws[(k + kk) * 64 + c0]);
#pragma unroll
            for (int j = 0; j < 4; j++) {
                float4 xv = *((const float4*)&Xs[(r0 + j) * XS_STRIDE + k]);
                acc[j][0] += xv.x * wv[0].x; acc[j][1] += xv.x * wv[0].y;
                acc[j][2] += xv.x * wv[0].z; acc[j][3] += xv.x * wv[0].w;
                acc[j][0] += xv.y * wv[1].x; acc[j][1] += xv.y * wv[1].y;
                acc[j][2] += xv.y * wv[1].z; acc[j][3] += xv.y * wv[1].w;
                acc[j][0] += xv.z * wv[2].x; acc[j][1] += xv.z * wv[2].y;
                acc[j][2] += xv.z * wv[2].z; acc[j][3] += xv.z * wv[2].w;
                acc[j][0] += xv.w * wv[3].x; acc[j][1] += xv.w * wv[3].y;
                acc[j][2] += xv.w * wv[3].z; acc[j][3] += xv.w * wv[3].w;
            }
        }
#pragma unroll
        for (int j = 0; j < 4; j++) {
            int row = rowBase + r0 + j;
            if (row < N) {
                __half2 h01 = __floats2half2_rn(acc[j][0], acc[j][1]);
                __half2 h23 = __floats2half2_rn(acc[j][2], acc[j][3]);
                uint2 pk;
                pk.x = *(unsigned int*)&h01;
                pk.y = *(unsigned int*)&h23;
                *((uint2*)(Hh + (size_t)row * 64 + c0)) = pk;
            }
        }
    } else {
        float* outF = (float*)OutP;
        for (int idx = tid; idx < 640; idx += 256) {
            int ln = idx / 10;
            int cl = idx - ln * 10;
            float acc = Wb[cl];
#pragma unroll
            for (int k = 0; k < 64; k += 4) {
                float4 xv = *((const float4*)&Xs[ln * XS_STRIDE + k]);
                float4 wv = *((const float4*)&Ws[cl * 64 + k]);
                acc += xv.x * wv.x;
                acc += xv.y * wv.y;
                acc += xv.z * wv.z;
                acc += xv.w * wv.w;
            }
            int row = rowBase + ln;
            if (row < N) outF[(size_t)row * 10 + cl] = acc;
        }
    }
}

extern "C" void kernel_launch(void* const* d_in, const int* in_sizes, int n_in,
                              void* d_out, int out_size, void* d_ws, size_t ws_size,
                              hipStream_t stream) {
    const float* x   = (const float*)d_in[0];
    const int*   src = (const int*)d_in[1];
    const int*   dst = (const int*)d_in[2];
    const float* W1  = (const float*)d_in[3];
    const float* b1  = (const float*)d_in[4];
    const float* W2  = (const float*)d_in[5];
    const float* b2  = (const float*)d_in[6];
    const float* W3  = (const float*)d_in[7];
    const float* b3  = (const float*)d_in[8];
    const float* Wfc = (const float*)d_in[9];
    const float* bfc = (const float*)d_in[10];
    float* out = (float*)d_out;
    int N = in_sizes[0] / 64;
    int E = in_sizes[1];
    int P = (E + CHUNK - 1) >> CHUNK_SHIFT;   // hist blocks per direction
    int words = (N + 3) / 4;                  // packed 4 bins per u32

    char* ws = (char*)d_ws;
    size_t p = 0;
    auto alloc = [&](size_t bytes) -> void* {
        void* r = ws + p;
        p = (p + bytes + 255) & ~(size_t)255;
        return r;
    };
    int*    deg_d = (int*)alloc((size_t)N * 4);
    int*    rp    = (int*)alloc((size_t)N * 4);
    int*    bsum  = (int*)alloc((size_t)THREADS * 4);
    unsigned char* rank = (unsigned char*)alloc((size_t)E);
    int*    col   = (int*)alloc((size_t)E * 4);
    float*  ns    = (float*)alloc((size_t)N * 4);
    float*  nd    = (float*)alloc((size_t)N * 4);
    unsigned int* partS = (unsigned int*)alloc((size_t)P * words * 4);
    unsigned int* partD = (unsigned int*)alloc((size_t)P * words * 4);
    unsigned int* prefD = (unsigned int*)alloc((size_t)P * words * 4);
    __half* bufH  = (__half*)alloc((size_t)N * 64 * 2);
    __half* bufH2 = (__half*)alloc((size_t)N * 64 * 2);
    unsigned int* counter = (unsigned int*)alloc(4);
    (void)ws_size; (void)n_in; (void)out_size;

    int gFill = (E + 255) / 256;
    int gP = (words + 63) / 64;     // block covers 64 words = 256 nodes
    int gG = (N + 63) / 64;

    k_hist<<<2 * P, 1024, 0, stream>>>(src, dst, partS, partD, rank, counter, E, P, words);
    k_pre <<<gP, THREADS, 0, stream>>>(partS, partD, prefD, deg_d, ns, nd,
                                       rp, bsum, counter, P, words, N);
    k_fill_gemm<<<gFill + gG, 256, 0, stream>>>(src, dst, rp, bsum, rank, prefD,
                                                col, E, words, gFill,
                                                x, ns, W1, bufH, N);
    k_agg_gemm<0><<<gG, 256, 0, stream>>>((const uint4*)bufH,  rp, bsum, deg_d, col,
                                          nd, ns, b1, W2, nullptr, bufH2, N);
    k_agg_gemm<0><<<gG, 256, 0, stream>>>((const uint4*)bufH2, rp, bsum, deg_d, col,
                                          nd, ns, b2, W3, nullptr, bufH, N);
    k_agg_gemm<1><<<gG, 256, 0, stream>>>((const uint4*)bufH,  rp, bsum, deg_d, col,
                                          nd, ns, b3, Wfc, bfc, out, N);
}

// Round 2
// 214.848 us; speedup vs baseline: 1.0689x; 1.0023x over previous
//
#include <hip/hip_runtime.h>
#include <hip/hip_fp16.h>
#include <math.h>

#define THREADS 256
#define CHUNK_SHIFT 15
#define CHUNK (1 << CHUNK_SHIFT)
#define LDS_WORDS 12500   // ceil(N/4) for N=50000, 8-bit packed counters
#define MAXB 16           // max chunks per quarter in k_pre (holds for P <= 64)
#define XS_STRIDE 68

// ---- privatized LDS histogram, 4 bins/word (8-bit); dst blocks capture rank ----
// Also zeroes the global row-base counter used by k_pre's atomic block-base claim.
__global__ __launch_bounds__(1024)
void k_hist(const int* __restrict__ src, const int* __restrict__ dst,
            unsigned int* __restrict__ partS, unsigned int* __restrict__ partD,
            unsigned char* __restrict__ rank, unsigned int* __restrict__ counter,
            int E, int P, int words) {
    __shared__ unsigned int hist[LDS_WORDS];
    if (blockIdx.x == 0 && threadIdx.x == 0) *counter = 0u;
    int isSrc = (blockIdx.x >= (unsigned)P);
    int b = isSrc ? (blockIdx.x - P) : blockIdx.x;
    int tid = threadIdx.x;

    for (int w = tid; w < words; w += 1024) hist[w] = 0u;
    __syncthreads();

    int start = b << CHUNK_SHIFT;
    int end = start + CHUNK; if (end > E) end = E;

    if (isSrc) {
        for (int e = start + tid; e < end; e += 1024) {
            int s = src[e];
            atomicAdd(&hist[s >> 2], 1u << ((s & 3) * 8));
        }
    } else {
        for (int e = start + tid; e < end; e += 1024) {
            int d = dst[e];
            unsigned int old = atomicAdd(&hist[d >> 2], 1u << ((d & 3) * 8));
            rank[e] = (unsigned char)((old >> ((d & 3) * 8)) & 0xFFu);
        }
    }
    __syncthreads();

    unsigned int* part = isSrc ? partS : partD;
    for (int w = tid; w < words; w += 1024)
        part[(size_t)b * words + w] = hist[w];
}

// ---- k_pre: one packed word (4 nodes) per thread, chunk range split 4-way.
// SWAR byte prefix in registers; block row-base claimed by atomicAdd
// (CSR row order is irrelevant for sum-aggregation) -> no separate scan kernel.
__global__ __launch_bounds__(THREADS)
void k_pre(const unsigned int* __restrict__ partS,
           const unsigned int* __restrict__ partD,
           unsigned int* __restrict__ prefD,
           int* __restrict__ deg_d, float* __restrict__ ns, float* __restrict__ nd,
           int* __restrict__ rp, int* __restrict__ bsum,
           unsigned int* __restrict__ counter,
           int P, int words, int N) {
    __shared__ unsigned int qsD[4][64];
    __shared__ unsigned int qsS[4][64];
    int t = threadIdx.x;
    int widx = t & 63;          // word within this block's 64-word span
    int q = t >> 6;             // chunk-range quarter
    int w = blockIdx.x * 64 + widx;
    bool valid = (w < words);

    int per = (P + 3) >> 2;     // <= MAXB for P <= 64
    int blo = q * per;
    int cnt = P - blo; if (cnt > per) cnt = per; if (cnt < 0) cnt = 0;

    unsigned int vD[MAXB];      // compile-time-indexed -> registers
    unsigned int runD = 0, runS = 0;
#pragma unroll
    for (int bb = 0; bb < MAXB; bb++) {
        unsigned int vd = 0, vs = 0;
        if (bb < cnt && valid) {
            size_t off = (size_t)(blo + bb) * words + w;
            vd = partD[off];
            vs = partS[off];
        }
        vD[bb] = vd;
        runD += vd;             // SWAR byte add: per-node totals < 256, no carry
        runS += vs;
    }
    qsD[q][widx] = runD;
    qsS[q][widx] = runS;
    __syncthreads();

    unsigned int baseD = 0, totD = 0, totS = 0;
#pragma unroll
    for (int qq = 0; qq < 4; qq++) {
        unsigned int xd = qsD[qq][widx];
        unsigned int xs = qsS[qq][widx];
        if (qq < q) baseD += xd;
        totD += xd;
        totS += xs;
    }

    // packed exclusive-prefix words for this quarter's chunk range
    unsigned int pref = baseD;
#pragma unroll
    for (int bb = 0; bb < MAXB; bb++) {
        if (bb < cnt && valid)
            prefD[(size_t)(blo + bb) * words + w] = pref;
        pref += vD[bb];
    }

    if (q == 0) {   // threads 0..63 == wave 0: per-node outputs + block scan
        int b0 = (int)(totD & 0xFFu), b1 = (int)((totD >> 8) & 0xFFu),
            b2 = (int)((totD >> 16) & 0xFFu), b3 = (int)((totD >> 24) & 0xFFu);
        int wsum = b0 + b1 + b2 + b3;
        int incl = wsum;
#pragma unroll
        for (int off = 1; off < 64; off <<= 1) {
            int y = __shfl_up(incl, off);
            if (widx >= off) incl += y;
        }
        int excl = incl - wsum;
        int btot = __shfl(incl, 63);
        if (widx == 0)
            bsum[blockIdx.x] = (int)atomicAdd(counter, (unsigned int)btot);
        if (valid) {
            int s0 = (int)(totS & 0xFFu), s1 = (int)((totS >> 8) & 0xFFu),
                s2 = (int)((totS >> 16) & 0xFFu), s3 = (int)((totS >> 24) & 0xFFu);
            int4 dv; dv.x = b0; dv.y = b1; dv.z = b2; dv.w = b3;
            *(int4*)&deg_d[(size_t)4 * w] = dv;
            float4 ndv;
            ndv.x = b0 ? 1.0f / sqrtf((float)b0) : 0.0f;
            ndv.y = b1 ? 1.0f / sqrtf((float)b1) : 0.0f;
            ndv.z = b2 ? 1.0f / sqrtf((float)b2) : 0.0f;
            ndv.w = b3 ? 1.0f / sqrtf((float)b3) : 0.0f;
            *(float4*)&nd[(size_t)4 * w] = ndv;
            float4 nsv;
            nsv.x = s0 ? 1.0f / sqrtf((float)s0) : 0.0f;
            nsv.y = s1 ? 1.0f / sqrtf((float)s1) : 0.0f;
            nsv.z = s2 ? 1.0f / sqrtf((float)s2) : 0.0f;
            nsv.w = s3 ? 1.0f / sqrtf((float)s3) : 0.0f;
            *(float4*)&ns[(size_t)4 * w] = nsv;
            int4 rv; rv.x = excl; rv.y = excl + b0;
            rv.z = excl + b0 + b1; rv.w = excl + b0 + b1 + b2;
            *(int4*)&rp[(size_t)4 * w] = rv;
        }
    }
}

// ---- merged: CSR fill (blocks [0,gFill)) || layer-1 GEMM (blocks [gFill, ...)) ----
__global__ __launch_bounds__(256, 4)
void k_fill_gemm(const int* __restrict__ src, const int* __restrict__ dst,
                 const int* __restrict__ rp, const int* __restrict__ bsum,
                 const unsigned char* __restrict__ rank,
                 const unsigned int* __restrict__ prefD,
                 int* __restrict__ col, int E, int words, int gFill,
                 const float* __restrict__ X, const float* __restrict__ norm,
                 const float* __restrict__ W, __half* __restrict__ H, int N) {
    __shared__ float Xs[64 * XS_STRIDE];
    __shared__ float Ws[64 * 64];
    int tid = threadIdx.x;

    if ((int)blockIdx.x < gFill) {
        int e = blockIdx.x * 256 + tid;
        if (e < E) {
            int d = dst[e];
            int b = e >> CHUNK_SHIFT;
            unsigned int pk = prefD[(size_t)b * words + (d >> 2)];
            int pref = (int)((pk >> ((d & 3) * 8)) & 0xFFu);
            col[rp[d] + bsum[d >> 8] + pref + (int)rank[e]] = src[e];
        }
        return;
    }

    int rowBase = ((int)blockIdx.x - gFill) * 64;
    for (int i = tid; i < 1024; i += 256)
        ((float4*)Ws)[i] = ((const float4*)W)[i];
    for (int i = tid; i < 1024; i += 256) {
        int r  = i >> 4;
        int k4 = i & 15;
        int row = rowBase + r;
        float4 v = make_float4(0.f, 0.f, 0.f, 0.f);
        if (row < N) {
            v = ((const float4*)X)[(size_t)row * 16 + k4];
            float nv = norm[row];
            v.x *= nv; v.y *= nv; v.z *= nv; v.w *= nv;
        }
        *((float4*)&Xs[r * XS_STRIDE + (k4 << 2)]) = v;
    }
    __syncthreads();

    int tc = tid & 15;
    int tr = tid >> 4;
    int c0 = tc * 4, r0 = tr * 4;
    float acc[4][4] = {};

#pragma unroll 2
    for (int k = 0; k < 64; k += 4) {
        float4 wv[4];
#pragma unroll
        for (int kk = 0; kk < 4; kk++)
            wv[kk] = *((const float4*)&Ws[(k + kk) * 64 + c0]);
#pragma unroll
        for (int j = 0; j < 4; j++) {
            float4 xv = *((const float4*)&Xs[(r0 + j) * XS_STRIDE + k]);
            acc[j][0] += xv.x * wv[0].x; acc[j][1] += xv.x * wv[0].y;
            acc[j][2] += xv.x * wv[0].z; acc[j][3] += xv.x * wv[0].w;
            acc[j][0] += xv.y * wv[1].x; acc[j][1] += xv.y * wv[1].y;
            acc[j][2] += xv.y * wv[1].z; acc[j][3] += xv.y * wv[1].w;
            acc[j][0] += xv.z * wv[2].x; acc[j][1] += xv.z * wv[2].y;
            acc[j][2] += xv.z * wv[2].z; acc[j][3] += xv.z * wv[2].w;
            acc[j][0] += xv.w * wv[3].x; acc[j][1] += xv.w * wv[3].y;
            acc[j][2] += xv.w * wv[3].z; acc[j][3] += xv.w * wv[3].w;
        }
    }
#pragma unroll
    for (int j = 0; j < 4; j++) {
        int row = rowBase + r0 + j;
        if (row < N) {
            __half2 h01 = __floats2half2_rn(acc[j][0], acc[j][1]);
            __half2 h23 = __floats2half2_rn(acc[j][2], acc[j][3]);
            uint2 pk;
            pk.x = *(unsigned int*)&h01;
            pk.y = *(unsigned int*)&h23;
            *((uint2*)(H + (size_t)row * 64 + c0)) = pk;
        }
    }
}

// ---- fused agg + next-layer GEMM (FC=0) or agg + final FC (FC=1).
// Phase A rework: 8 nodes in flight per wave (group g = lane>>3 owns a node;
// lane slot l = lane&7 owns channels 8l..8l+7). All per-edge gathers are
// independent loads; first col batch preloaded for both rounds; next batch
// software-prefetched. No butterfly reduce, no readfirstlane serialization.
template<int FC>
__global__ __launch_bounds__(256, 4)
void k_agg_gemm(const uint4* __restrict__ H4, const int* __restrict__ rp,
                const int* __restrict__ bsum, const int* __restrict__ deg,
                const int* __restrict__ col, const float* __restrict__ nd,
                const float* __restrict__ nsrc, const float* __restrict__ bias,
                const float* __restrict__ W, const float* __restrict__ Wb2,
                void* __restrict__ OutP, int N) {
    __shared__ float Xs[64 * XS_STRIDE];
    __shared__ float Ws[FC ? 640 : 4096];
    __shared__ float Wb[16];
    int tid = threadIdx.x;

    if constexpr (FC == 0) {
        for (int i = tid; i < 1024; i += 256)
            ((float4*)Ws)[i] = ((const float4*)W)[i];
    } else {
        // store transposed: Ws[c*64 + k] = Wfc[k][c]
        for (int i = tid; i < 640; i += 256) {
            int k = i / 10, c = i - k * 10;
            Ws[c * 64 + k] = W[i];
        }
        if (tid < 10) Wb[tid] = Wb2[tid];
    }

    int wave = tid >> 6;
    int lane = tid & 63;
    int g = lane >> 3;   // node sub-index within a round
    int l = lane & 7;    // uint4 slot: channels 8l..8l+7
    int rowBase = blockIdx.x * 64;

    float4 bv0 = *((const float4*)&bias[l * 8]);
    float4 bv1 = *((const float4*)&bias[l * 8 + 4]);

    // ---- phase A: two rounds of 8 concurrent nodes per wave
    int nodeA = rowBase + wave * 16 + g;
    int nodeB = nodeA + 8;

    int stA = 0, nA = 0; float nvA = 0.f, nsA = 0.f;
    if (nodeA < N) {
        stA = rp[nodeA] + bsum[nodeA >> 8];
        nA  = deg[nodeA];
        nvA = nd[nodeA];
        if constexpr (FC == 0) nsA = nsrc[nodeA];
    }
    int stB = 0, nB = 0; float nvB = 0.f, nsB = 0.f;
    if (nodeB < N) {
        stB = rp[nodeB] + bsum[nodeB >> 8];
        nB  = deg[nodeB];
        nvB = nd[nodeB];
        if constexpr (FC == 0) nsB = nsrc[nodeB];
    }

    // preload first col batch for both rounds (independent -> overlapped)
    int idxA = (l < nA) ? col[stA + l] : 0;
    int idxB = (l < nB) ? col[stB + l] : 0;

    // wave-uniform loop bounds (max deg across the 8 groups)
    int mA = nA, mB = nB;
#pragma unroll
    for (int d = 8; d <= 32; d <<= 1) {
        int tA = __shfl_xor(mA, d); mA = mA > tA ? mA : tA;
        int tB = __shfl_xor(mB, d); mB = mB > tB ? mB : tB;
    }

    auto run = [&](int start, int n, int m, int idx, float nv, float nsv,
                   bool vn, int row) {
        float acc[8] = {0.f, 0.f, 0.f, 0.f, 0.f, 0.f, 0.f, 0.f};
        for (int j0 = 0; j0 < m; j0 += 8) {
            // prefetch next batch's indices (predicated; no OOB)
            int idxn = ((j0 + 8 + l) < n) ? col[start + j0 + 8 + l] : 0;
#pragma unroll
            for (int jj = 0; jj < 8; jj++) {
                int s = __shfl(idx, (g << 3) + jj);
                if (j0 + jj < n) {
                    uint4 v = H4[(size_t)s * 8 + l];
                    float2 f0 = __half22float2(*(__half2*)&v.x);
                    float2 f1 = __half22float2(*(__half2*)&v.y);
                    float2 f2 = __half22float2(*(__half2*)&v.z);
                    float2 f3 = __half22float2(*(__half2*)&v.w);
                    acc[0] += f0.x; acc[1] += f0.y; acc[2] += f1.x; acc[3] += f1.y;
                    acc[4] += f2.x; acc[5] += f2.y; acc[6] += f3.x; acc[7] += f3.y;
                }
            }
            idx = idxn;
        }
        float4 o0, o1;
        o0.x = tanhf(acc[0] * nv + bv0.x);
        o0.y = tanhf(acc[1] * nv + bv0.y);
        o0.z = tanhf(acc[2] * nv + bv0.z);
        o0.w = tanhf(acc[3] * nv + bv0.w);
        o1.x = tanhf(acc[4] * nv + bv1.x);
        o1.y = tanhf(acc[5] * nv + bv1.y);
        o1.z = tanhf(acc[6] * nv + bv1.z);
        o1.w = tanhf(acc[7] * nv + bv1.w);
        if constexpr (FC == 0) {   // pre-scale by ns for next GEMM
            o0.x *= nsv; o0.y *= nsv; o0.z *= nsv; o0.w *= nsv;
            o1.x *= nsv; o1.y *= nsv; o1.z *= nsv; o1.w *= nsv;
        }
        if (!vn) {
            o0 = make_float4(0.f, 0.f, 0.f, 0.f);
            o1 = make_float4(0.f, 0.f, 0.f, 0.f);
        }
        *((float4*)&Xs[row * XS_STRIDE + l * 8])     = o0;
        *((float4*)&Xs[row * XS_STRIDE + l * 8 + 4]) = o1;
    };

    run(stA, nA, mA, idxA, nvA, nsA, nodeA < N, wave * 16 + g);
    run(stB, nB, mB, idxB, nvB, nsB, nodeB < N, wave * 16 + 8 + g);
    __syncthreads();

    // ---- phase B
    if constexpr (FC == 0) {
        __half* Hh = (__half*)OutP;
        int tc = tid & 15;
        int tr = tid >> 4;
        int c0 = tc * 4, r0 = tr * 4;
        float acc[4][4] = {};

#pragma unroll 2
        for (int k = 0; k < 64; k += 4) {
            float4 wv[4];
#pragma unroll
            for (int kk = 0; kk < 4; kk++)
                wv[kk] = *((const float4*)&Ws[(k + kk) * 64 + c0]);
#pragma unroll
            for (int j = 0; j < 4; j++) {
                float4 xv = *((const float4*)&Xs[(r0 + j) * XS_STRIDE + k]);
                acc[j][0] += xv.x * wv[0].x; acc[j][1] += xv.x * wv[0].y;
                acc[j][2] += xv.x * wv[0].z; acc[j][3] += xv.x * wv[0].w;
                acc[j][0] += xv.y * wv[1].x; acc[j][1] += xv.y * wv[1].y;
                acc[j][2] += xv.y * wv[1].z; acc[j][3] += xv.y * wv[1].w;
                acc[j][0] += xv.z * wv[2].x; acc[j][1] += xv.z * wv[2].y;
                acc[j][2] += xv.z * wv[2].z; acc[j][3] += xv.z * wv[2].w;
                acc[j][0] += xv.w * wv[3].x; acc[j][1] += xv.w * wv[3].y;
                acc[j][2] += xv.w * wv[3].z; acc[j][3] += xv.w * wv[3].w;
            }
        }
#pragma unroll
        for (int j = 0; j < 4; j++) {
            int row = rowBase + r0 + j;
            if (row < N) {
                __half2 h01 = __floats2half2_rn(acc[j][0], acc[j][1]);
                __half2 h23 = __floats2half2_rn(acc[j][2], acc[j][3]);
                uint2 pk;
                pk.x = *(unsigned int*)&h01;
                pk.y = *(unsigned int*)&h23;
                *((uint2*)(Hh + (size_t)row * 64 + c0)) = pk;
            }
        }
    } else {
        float* outF = (float*)OutP;
        for (int idx = tid; idx < 640; idx += 256) {
            int ln = idx / 10;
            int cl = idx - ln * 10;
            float acc = Wb[cl];
#pragma unroll
            for (int k = 0; k < 64; k += 4) {
                float4 xv = *((const float4*)&Xs[ln * XS_STRIDE + k]);
                float4 wv = *((const float4*)&Ws[cl * 64 + k]);
                acc += xv.x * wv.x;
                acc += xv.y * wv.y;
                acc += xv.z * wv.z;
                acc += xv.w * wv.w;
            }
            int row = rowBase + ln;
            if (row < N) outF[(size_t)row * 10 + cl] = acc;
        }
    }
}

extern "C" void kernel_launch(void* const* d_in, const int* in_sizes, int n_in,
                              void* d_out, int out_size, void* d_ws, size_t ws_size,
                              hipStream_t stream) {
    const float* x   = (const float*)d_in[0];
    const int*   src = (const int*)d_in[1];
    const int*   dst = (const int*)d_in[2];
    const float* W1  = (const float*)d_in[3];
    const float* b1  = (const float*)d_in[4];
    const float* W2  = (const float*)d_in[5];
    const float* b2  = (const float*)d_in[6];
    const float* W3  = (const float*)d_in[7];
    const float* b3  = (const float*)d_in[8];
    const float* Wfc = (const float*)d_in[9];
    const float* bfc = (const float*)d_in[10];
    float* out = (float*)d_out;
    int N = in_sizes[0] / 64;
    int E = in_sizes[1];
    int P = (E + CHUNK - 1) >> CHUNK_SHIFT;   // hist blocks per direction
    int words = (N + 3) / 4;                  // packed 4 bins per u32

    char* ws = (char*)d_ws;
    size_t p = 0;
    auto alloc = [&](size_t bytes) -> void* {
        void* r = ws + p;
        p = (p + bytes + 255) & ~(size_t)255;
        return r;
    };
    int*    deg_d = (int*)alloc((size_t)N * 4);
    int*    rp    = (int*)alloc((size_t)N * 4);
    int*    bsum  = (int*)alloc((size_t)THREADS * 4);
    unsigned char* rank = (unsigned char*)alloc((size_t)E);
    int*    col   = (int*)alloc((size_t)E * 4);
    float*  ns    = (float*)alloc((size_t)N * 4);
    float*  nd    = (float*)alloc((size_t)N * 4);
    unsigned int* partS = (unsigned int*)alloc((size_t)P * words * 4);
    unsigned int* partD = (unsigned int*)alloc((size_t)P * words * 4);
    unsigned int* prefD = (unsigned int*)alloc((size_t)P * words * 4);
    __half* bufH  = (__half*)alloc((size_t)N * 64 * 2);
    __half* bufH2 = (__half*)alloc((size_t)N * 64 * 2);
    unsigned int* counter = (unsigned int*)alloc(4);
    (void)ws_size; (void)n_in; (void)out_size;

    int gFill = (E + 255) / 256;
    int gP = (words + 63) / 64;     // block covers 64 words = 256 nodes
    int gG = (N + 63) / 64;

    k_hist<<<2 * P, 1024, 0, stream>>>(src, dst, partS, partD, rank, counter, E, P, words);
    k_pre <<<gP, THREADS, 0, stream>>>(partS, partD, prefD, deg_d, ns, nd,
                                       rp, bsum, counter, P, words, N);
    k_fill_gemm<<<gFill + gG, 256, 0, stream>>>(src, dst, rp, bsum, rank, prefD,
                                                col, E, words, gFill,
                                                x, ns, W1, bufH, N);
    k_agg_gemm<0><<<gG, 256, 0, stream>>>((const uint4*)bufH,  rp, bsum, deg_d, col,
                                          nd, ns, b1, W2, nullptr, bufH2, N);
    k_agg_gemm<0><<<gG, 256, 0, stream>>>((const uint4*)bufH2, rp, bsum, deg_d, col,
                                          nd, ns, b2, W3, nullptr, bufH, N);
    k_agg_gemm<1><<<gG, 256, 0, stream>>>((const uint4*)bufH,  rp, bsum, deg_d, col,
                                          nd, ns, b3, Wfc, bfc, out, N);
}